// Round 2
// baseline (767.705 us; speedup 1.0000x reference)
//
#include <hip/hip_runtime.h>

#define D_IN  128
#define D_H   64
#define D_OUT 40

// ---------------- degree / CSR build ----------------

static __global__ void k_zero(int* p, int n){
  int i = blockIdx.x*256 + threadIdx.x;
  if (i < n) p[i] = 0;
}

static __global__ void k_count(const int* __restrict__ dst, int* __restrict__ deg, int E){
  int i = blockIdx.x*256 + threadIdx.x;
  if (i < E) atomicAdd(&deg[dst[i]], 1);
}

static __global__ void k_scan1(const int* __restrict__ deg, int* __restrict__ incl,
                               int* __restrict__ bsums, int n){
  __shared__ int s[1024];
  int t = threadIdx.x; int g = blockIdx.x*1024 + t;
  int v = (g < n) ? deg[g] : 0;
  s[t] = v; __syncthreads();
  for (int off = 1; off < 1024; off <<= 1){
    int u = (t >= off) ? s[t-off] : 0; __syncthreads();
    s[t] += u; __syncthreads();
  }
  if (g < n) incl[g] = s[t];
  if (t == 1023) bsums[blockIdx.x] = s[1023];
}

static __global__ void k_scan2(int* bsums, int nb){
  __shared__ int s[128];
  int t = threadIdx.x;
  int v = (t < nb) ? bsums[t] : 0;
  s[t] = v; __syncthreads();
  for (int off = 1; off < 128; off <<= 1){
    int u = (t >= off) ? s[t-off] : 0; __syncthreads();
    s[t] += u; __syncthreads();
  }
  if (t < nb) bsums[t] = s[t] - v;   // exclusive block offsets
}

static __global__ void k_scan3(const int* __restrict__ deg, int* __restrict__ rs,
                               const int* __restrict__ bsums, int* __restrict__ cursor,
                               float* __restrict__ dinv, int n){
  int t = threadIdx.x; int g = blockIdx.x*1024 + t;
  if (g < n){
    int excl = rs[g] - deg[g] + bsums[blockIdx.x];
    rs[g] = excl; cursor[g] = excl;
    dinv[g] = rsqrtf((float)(deg[g] + 1));   // +1 = self loop
  }
}

static __global__ void k_fill(const int* __restrict__ src, const int* __restrict__ dst,
                              int* __restrict__ cursor, int* __restrict__ col, int E){
  int i = blockIdx.x*256 + threadIdx.x;
  if (i < E){ int p = atomicAdd(&cursor[dst[i]], 1); col[p] = src[i]; }
}

// ---------------- fold delete-MLP into GEMM2: M = Wd1^T @ Wc2, bvec = bd1 @ Wc2 -----

static __global__ void k_pre(const float* __restrict__ Wd1, const float* __restrict__ bd1,
                             const float* __restrict__ Wc2, float* __restrict__ M,
                             float* __restrict__ bvec){
  int t = threadIdx.x;
  for (int i = t; i < D_H*D_OUT; i += 256){
    int q = i / D_OUT, j = i % D_OUT;
    float s = 0.f;
    for (int k = 0; k < D_H; k++) s += Wd1[k*D_H + q] * Wc2[k*D_OUT + j];
    M[i] = s;
  }
  if (t < D_OUT){
    float s = 0.f;
    for (int k = 0; k < D_H; k++) s += bd1[k] * Wc2[k*D_OUT + t];
    bvec[t] = s;
  }
}

// ---------------- GEMM1: hws1[n] = dinv[n] * (x[n] @ Wc1) ----------------

__launch_bounds__(256)
static __global__ void k_gemm1(const float* __restrict__ x, const float* __restrict__ Wc1,
                               const float* __restrict__ dinv, float* __restrict__ hws1, int n){
  __shared__ float Wl[D_IN*D_H];        // 32 KB
  __shared__ float xs[32][D_IN+1];      // padded
  int t = threadIdx.x;
  int base = blockIdx.x*32;
  for (int i = t; i < D_IN*D_H; i += 256) Wl[i] = Wc1[i];
  for (int i = t; i < 32*D_IN; i += 256){
    int r = i >> 7, c = i & 127;
    int node = base + r;
    xs[r][c] = (node < n) ? x[(size_t)node*D_IN + c] : 0.f;
  }
  __syncthreads();
  int nl = t >> 3, j0 = (t & 7)*8;
  int node = base + nl;
  if (node >= n) return;
  float acc[8] = {0,0,0,0,0,0,0,0};
  #pragma unroll 4
  for (int k = 0; k < D_IN; k++){
    float xv = xs[nl][k];
    #pragma unroll
    for (int jj = 0; jj < 8; jj++) acc[jj] += xv * Wl[k*D_H + j0 + jj];
  }
  float dv = dinv[node];
  float4 o0 = make_float4(acc[0]*dv, acc[1]*dv, acc[2]*dv, acc[3]*dv);
  float4 o1 = make_float4(acc[4]*dv, acc[5]*dv, acc[6]*dv, acc[7]*dv);
  float* op = hws1 + (size_t)node*D_H + j0;
  *(float4*)op = o0; *(float4*)(op+4) = o1;
}

// ---------------- agg1: h = relu(dinv * (self + sum_in) + bc1) ----------------

__launch_bounds__(256)
static __global__ void k_agg1(const float* __restrict__ hws1, const int* __restrict__ rs,
                              const int* __restrict__ deg, const int* __restrict__ col,
                              const float* __restrict__ dinv, const float* __restrict__ bc1,
                              float* __restrict__ h, int n){
  int t = threadIdx.x;
  int wave = t >> 6, lane = t & 63;
  int node = blockIdx.x*4 + wave;
  if (node >= n) return;
  float acc = hws1[(size_t)node*D_H + lane];      // self loop
  int s0 = rs[node], cnt = deg[node];
  for (int e = 0; e < cnt; e++){
    int s = col[s0 + e];
    acc += hws1[(size_t)s*D_H + lane];
  }
  float v = acc*dinv[node] + bc1[lane];
  h[(size_t)node*D_H + lane] = fmaxf(v, 0.f);
}

// ---------------- GEMM2 (+ folded delete MLP): hws2[n] = dinv[n] * (h[n] @ (mask? M:Wc2)) --

__launch_bounds__(128)
static __global__ void k_gemm2(const float* __restrict__ h, const unsigned char* __restrict__ mask,
                               const float* __restrict__ Mmat, const float* __restrict__ bvec,
                               const float* __restrict__ Wc2, const float* __restrict__ dinv,
                               float* __restrict__ hws2, int n){
  __shared__ float Ms[D_H*D_OUT];          // 10 KB
  __shared__ float Ws[D_H*D_OUT];          // 10 KB
  __shared__ float bv[D_OUT];
  __shared__ float hs[128*(D_H+1)];        // 33.3 KB, padded stride 65
  int t = threadIdx.x;
  int base = blockIdx.x*128;
  for (int i = t; i < D_H*D_OUT; i += 128){ Ms[i] = Mmat[i]; Ws[i] = Wc2[i]; }
  if (t < D_OUT) bv[t] = bvec[t];
  for (int i = t; i < 128*D_H; i += 128){
    int r = i >> 6, c = i & 63;
    int node = base + r;
    hs[r*(D_H+1) + c] = (node < n) ? h[(size_t)node*D_H + c] : 0.f;
  }
  __syncthreads();
  int node = base + t;
  if (node >= n) return;
  bool m = mask[node] != 0;
  const float* Wp = m ? Ms : Ws;
  float acc[D_OUT];
  #pragma unroll
  for (int j = 0; j < D_OUT; j++) acc[j] = m ? bv[j] : 0.f;
  const float* hrow = &hs[t*(D_H+1)];
  for (int q = 0; q < D_H; q++){
    float hv = hrow[q];
    #pragma unroll
    for (int j = 0; j < D_OUT; j++) acc[j] += hv * Wp[q*D_OUT + j];
  }
  float dv = dinv[node];
  float* op = hws2 + (size_t)node*D_OUT;
  #pragma unroll
  for (int j = 0; j < D_OUT; j++) op[j] = acc[j]*dv;
}

// ---------------- agg2 + final delete epilogue -> out ----------------

__launch_bounds__(256)
static __global__ void k_agg2(const float* __restrict__ hws2, const int* __restrict__ rs,
                              const int* __restrict__ deg, const int* __restrict__ col,
                              const float* __restrict__ dinv, const float* __restrict__ bc2,
                              const unsigned char* __restrict__ mask,
                              const float* __restrict__ Wd2, const float* __restrict__ bd2,
                              float* __restrict__ out, int n){
  __shared__ float wds[D_OUT*41];          // stride-41 pad
  __shared__ float bds[D_OUT];
  int t = threadIdx.x;
  for (int i = t; i < D_OUT*D_OUT; i += 256){
    int j = i / D_OUT, k = i % D_OUT;
    wds[j*41 + k] = Wd2[i];
  }
  if (t < D_OUT) bds[t] = bd2[t];
  __syncthreads();
  int wave = t >> 6, lane = t & 63;
  int node = blockIdx.x*4 + wave;
  if (node >= n) return;
  float acc = 0.f;
  if (lane < D_OUT) acc = hws2[(size_t)node*D_OUT + lane];   // self loop
  int s0 = rs[node], cnt = deg[node];
  for (int e = 0; e < cnt; e++){
    int s = col[s0 + e];
    if (lane < D_OUT) acc += hws2[(size_t)s*D_OUT + lane];
  }
  float res = (lane < D_OUT) ? (acc*dinv[node] + bc2[lane]) : 0.f;
  if (mask[node] != 0){                     // wave-uniform branch
    // register-only broadcast: no LDS RAW ordering assumption
    float s_ = (lane < D_OUT) ? bds[lane] : 0.f;
    #pragma unroll
    for (int k = 0; k < D_OUT; k++){
      float v = __shfl(res, k, 64);
      s_ += v * wds[lane*41 + k];
    }
    if (lane < D_OUT) res = s_;
  }
  if (lane < D_OUT) out[(size_t)node*D_OUT + lane] = res;
}

// ---------------- launcher ----------------

extern "C" void kernel_launch(void* const* d_in, const int* in_sizes, int n_in,
                              void* d_out, int out_size, void* d_ws, size_t ws_size,
                              hipStream_t stream){
  const float* x    = (const float*)d_in[0];
  const int*   ei   = (const int*)d_in[1];
  const unsigned char* mask = (const unsigned char*)d_in[2];
  const float* Wc1  = (const float*)d_in[3];
  const float* bc1  = (const float*)d_in[4];
  const float* Wc2  = (const float*)d_in[5];
  const float* bc2  = (const float*)d_in[6];
  const float* Wd1  = (const float*)d_in[7];
  const float* bd1  = (const float*)d_in[8];
  const float* Wd2  = (const float*)d_in[9];
  const float* bd2  = (const float*)d_in[10];

  int N = in_sizes[0] / D_IN;
  int E = in_sizes[1] / 2;
  const int* src = ei;
  const int* dst = ei + E;
  float* out = (float*)d_out;

  char* w = (char*)d_ws; size_t off = 0;
  auto A = [&](size_t bytes)->void*{
    void* p = w + off;
    off += (bytes + 255) & ~(size_t)255;
    return p;
  };
  int*   deg    = (int*)  A((size_t)N*4);
  int*   rs     = (int*)  A((size_t)N*4);
  int*   cursor = (int*)  A((size_t)N*4);
  int*   bsums  = (int*)  A(256*4);
  float* dinv   = (float*)A((size_t)N*4);
  float* Mmat   = (float*)A((size_t)D_H*D_OUT*4);
  float* bvec   = (float*)A((size_t)D_OUT*4);
  int*   col    = (int*)  A((size_t)E*4);
  float* hws1   = (float*)A((size_t)N*D_H*4);
  float* h      = (float*)A((size_t)N*D_H*4);
  float* hws2   = hws1;   // hws1 dead after agg1 -> reuse

  int NB = (N + 1023) / 1024;

  hipLaunchKernelGGL(k_zero,  dim3((N+255)/256), dim3(256), 0, stream, deg, N);
  hipLaunchKernelGGL(k_count, dim3((E+255)/256), dim3(256), 0, stream, dst, deg, E);
  hipLaunchKernelGGL(k_scan1, dim3(NB), dim3(1024), 0, stream, deg, rs, bsums, N);
  hipLaunchKernelGGL(k_scan2, dim3(1), dim3(128), 0, stream, bsums, NB);
  hipLaunchKernelGGL(k_scan3, dim3(NB), dim3(1024), 0, stream, deg, rs, bsums, cursor, dinv, N);
  hipLaunchKernelGGL(k_fill,  dim3((E+255)/256), dim3(256), 0, stream, src, dst, cursor, col, E);
  hipLaunchKernelGGL(k_pre,   dim3(1), dim3(256), 0, stream, Wd1, bd1, Wc2, Mmat, bvec);
  hipLaunchKernelGGL(k_gemm1, dim3((N+31)/32), dim3(256), 0, stream, x, Wc1, dinv, hws1, N);
  hipLaunchKernelGGL(k_agg1,  dim3((N+3)/4), dim3(256), 0, stream, hws1, rs, deg, col, dinv, bc1, h, N);
  hipLaunchKernelGGL(k_gemm2, dim3((N+127)/128), dim3(128), 0, stream, h, mask, Mmat, bvec, Wc2, dinv, hws2, N);
  hipLaunchKernelGGL(k_agg2,  dim3((N+3)/4), dim3(256), 0, stream, hws2, rs, deg, col, dinv, bc2, mask, Wd2, bd2, out, N);
}

// Round 3
// 590.899 us; speedup vs baseline: 1.2992x; 1.2992x over previous
//
#include <hip/hip_runtime.h>

#define D_IN  128
#define D_H   64
#define D_OUT 40

// ---------------- degree / CSR build ----------------

static __global__ void k_count(const int* __restrict__ dst, int* __restrict__ deg, int E){
  int i = blockIdx.x*256 + threadIdx.x;
  if (i < E) atomicAdd(&deg[dst[i]], 1);
}

static __global__ void k_scan1(const int* __restrict__ deg, int* __restrict__ incl,
                               int* __restrict__ bsums, int n){
  __shared__ int s[1024];
  int t = threadIdx.x; int g = blockIdx.x*1024 + t;
  int v = (g < n) ? deg[g] : 0;
  s[t] = v; __syncthreads();
  for (int off = 1; off < 1024; off <<= 1){
    int u = (t >= off) ? s[t-off] : 0; __syncthreads();
    s[t] += u; __syncthreads();
  }
  if (g < n) incl[g] = s[t];
  if (t == 1023) bsums[blockIdx.x] = s[1023];
}

static __global__ void k_scan2(int* bsums, int nb){
  __shared__ int s[128];
  int t = threadIdx.x;
  int v = (t < nb) ? bsums[t] : 0;
  s[t] = v; __syncthreads();
  for (int off = 1; off < 128; off <<= 1){
    int u = (t >= off) ? s[t-off] : 0; __syncthreads();
    s[t] += u; __syncthreads();
  }
  if (t < nb) bsums[t] = s[t] - v;   // exclusive block offsets
}

static __global__ void k_scan3(const int* __restrict__ deg, int* __restrict__ rs,
                               const int* __restrict__ bsums, int* __restrict__ cursor,
                               float* __restrict__ dinv, int n){
  int t = threadIdx.x; int g = blockIdx.x*1024 + t;
  if (g < n){
    int excl = rs[g] - deg[g] + bsums[blockIdx.x];
    rs[g] = excl; cursor[g] = excl;
    dinv[g] = rsqrtf((float)(deg[g] + 1));   // +1 = self loop
  }
}

static __global__ void k_fill(const int* __restrict__ src, const int* __restrict__ dst,
                              int* __restrict__ cursor, int* __restrict__ col, int E){
  int i = blockIdx.x*256 + threadIdx.x;
  if (i < E){ int p = atomicAdd(&cursor[dst[i]], 1); col[p] = src[i]; }
}

// ---------------- fold delete-MLP into GEMM2: M = Wd1^T @ Wc2, bvec = bd1 @ Wc2 -----

static __global__ void k_pre(const float* __restrict__ Wd1, const float* __restrict__ bd1,
                             const float* __restrict__ Wc2, float* __restrict__ M,
                             float* __restrict__ bvec){
  int t = threadIdx.x;
  for (int i = t; i < D_H*D_OUT; i += 256){
    int q = i / D_OUT, j = i % D_OUT;
    float s = 0.f;
    for (int k = 0; k < D_H; k++) s += Wd1[k*D_H + q] * Wc2[k*D_OUT + j];
    M[i] = s;
  }
  if (t < D_OUT){
    float s = 0.f;
    for (int k = 0; k < D_H; k++) s += bd1[k] * Wc2[k*D_OUT + t];
    bvec[t] = s;
  }
}

// ---------------- GEMM1: hws1[n] = dinv[n] * (x[n] @ Wc1) ----------------

__launch_bounds__(256)
static __global__ void k_gemm1(const float* __restrict__ x, const float* __restrict__ Wc1,
                               const float* __restrict__ dinv, float* __restrict__ hws1, int n){
  __shared__ float Wl[D_IN*D_H];        // 32 KB
  __shared__ float xs[32][D_IN+1];      // padded
  int t = threadIdx.x;
  int base = blockIdx.x*32;
  for (int i = t; i < D_IN*D_H; i += 256) Wl[i] = Wc1[i];
  for (int i = t; i < 32*D_IN; i += 256){
    int r = i >> 7, c = i & 127;
    int node = base + r;
    xs[r][c] = (node < n) ? x[(size_t)node*D_IN + c] : 0.f;
  }
  __syncthreads();
  int nl = t >> 3, j0 = (t & 7)*8;
  int node = base + nl;
  if (node >= n) return;
  float acc[8] = {0,0,0,0,0,0,0,0};
  #pragma unroll 4
  for (int k = 0; k < D_IN; k++){
    float xv = xs[nl][k];
    #pragma unroll
    for (int jj = 0; jj < 8; jj++) acc[jj] += xv * Wl[k*D_H + j0 + jj];
  }
  float dv = dinv[node];
  float4 o0 = make_float4(acc[0]*dv, acc[1]*dv, acc[2]*dv, acc[3]*dv);
  float4 o1 = make_float4(acc[4]*dv, acc[5]*dv, acc[6]*dv, acc[7]*dv);
  float* op = hws1 + (size_t)node*D_H + j0;
  *(float4*)op = o0; *(float4*)(op+4) = o1;
}

// ---------------- agg1: h = relu(dinv * (self + sum_in) + bc1) ----------------
// 4 edges gathered per wave-instruction: 4 groups x 16 lanes x float4.

__launch_bounds__(256)
static __global__ void k_agg1(const float* __restrict__ hws1, const int* __restrict__ rs,
                              const int* __restrict__ deg, const int* __restrict__ col,
                              const float* __restrict__ dinv, const float* __restrict__ bc1,
                              float* __restrict__ h, int n){
  int t = threadIdx.x;
  int wave = t >> 6, lane = t & 63;
  int node = blockIdx.x*4 + wave;
  if (node >= n) return;
  int grp = lane >> 4, fl = lane & 15;
  const float4* h4 = (const float4*)hws1;
  float4 acc = make_float4(0.f, 0.f, 0.f, 0.f);
  if (grp == 0) acc = h4[(size_t)node*16 + fl];     // self loop
  int s0 = rs[node], cnt = deg[node];
  for (int cb = 0; cb < cnt; cb += 64){
    int m = cnt - cb; if (m > 64) m = 64;
    int idx = (lane < m) ? col[s0 + cb + lane] : 0;  // coalesced index prefetch
    #pragma unroll 4
    for (int e0 = 0; e0 < m; e0 += 4){
      int sl = e0 + grp;
      int s = __shfl(idx, sl, 64);
      if (sl < m){
        float4 v = h4[(size_t)s*16 + fl];
        acc.x += v.x; acc.y += v.y; acc.z += v.z; acc.w += v.w;
      }
    }
  }
  // combine the 4 groups
  acc.x += __shfl_xor(acc.x, 16, 64); acc.y += __shfl_xor(acc.y, 16, 64);
  acc.z += __shfl_xor(acc.z, 16, 64); acc.w += __shfl_xor(acc.w, 16, 64);
  acc.x += __shfl_xor(acc.x, 32, 64); acc.y += __shfl_xor(acc.y, 32, 64);
  acc.z += __shfl_xor(acc.z, 32, 64); acc.w += __shfl_xor(acc.w, 32, 64);
  if (grp == 0){
    float dv = dinv[node];
    float4 b = ((const float4*)bc1)[fl];
    float4 o;
    o.x = fmaxf(acc.x*dv + b.x, 0.f);
    o.y = fmaxf(acc.y*dv + b.y, 0.f);
    o.z = fmaxf(acc.z*dv + b.z, 0.f);
    o.w = fmaxf(acc.w*dv + b.w, 0.f);
    ((float4*)h)[(size_t)node*16 + fl] = o;
  }
}

// ---------------- GEMM2 (+ folded delete MLP): hws2[n] = dinv[n] * (h[n] @ (mask? M:Wc2)) --

__launch_bounds__(128)
static __global__ void k_gemm2(const float* __restrict__ h, const unsigned char* __restrict__ mask,
                               const float* __restrict__ Mmat, const float* __restrict__ bvec,
                               const float* __restrict__ Wc2, const float* __restrict__ dinv,
                               float* __restrict__ hws2, int n){
  __shared__ float Ms[D_H*D_OUT];          // 10 KB
  __shared__ float Ws[D_H*D_OUT];          // 10 KB
  __shared__ float bv[D_OUT];
  __shared__ float hs[128*(D_H+1)];        // 33.3 KB, padded stride 65
  int t = threadIdx.x;
  int base = blockIdx.x*128;
  for (int i = t; i < D_H*D_OUT; i += 128){ Ms[i] = Mmat[i]; Ws[i] = Wc2[i]; }
  if (t < D_OUT) bv[t] = bvec[t];
  for (int i = t; i < 128*D_H; i += 128){
    int r = i >> 6, c = i & 63;
    int node = base + r;
    hs[r*(D_H+1) + c] = (node < n) ? h[(size_t)node*D_H + c] : 0.f;
  }
  __syncthreads();
  int node = base + t;
  if (node >= n) return;
  bool m = mask[node] != 0;
  const float* Wp = m ? Ms : Ws;
  float acc[D_OUT];
  #pragma unroll
  for (int j = 0; j < D_OUT; j++) acc[j] = m ? bv[j] : 0.f;
  const float* hrow = &hs[t*(D_H+1)];
  for (int q = 0; q < D_H; q++){
    float hv = hrow[q];
    #pragma unroll
    for (int j = 0; j < D_OUT; j++) acc[j] += hv * Wp[q*D_OUT + j];
  }
  float dv = dinv[node];
  float* op = hws2 + (size_t)node*D_OUT;
  #pragma unroll
  for (int j = 0; j < D_OUT; j++) op[j] = acc[j]*dv;
}

// ---------------- agg2 + final delete epilogue -> out ----------------
// Same 4-edges-per-instruction structure; 10 of 16 lanes per group carry float4.

__launch_bounds__(256)
static __global__ void k_agg2(const float* __restrict__ hws2, const int* __restrict__ rs,
                              const int* __restrict__ deg, const int* __restrict__ col,
                              const float* __restrict__ dinv, const float* __restrict__ bc2,
                              const unsigned char* __restrict__ mask,
                              const float* __restrict__ Wd2, const float* __restrict__ bd2,
                              float* __restrict__ out, int n){
  __shared__ float wds[D_OUT*41];          // stride-41 pad -> <=2-way LDS conflict (free)
  __shared__ float bds[D_OUT];
  int t = threadIdx.x;
  for (int i = t; i < D_OUT*D_OUT; i += 256){
    int j = i / D_OUT, k = i % D_OUT;
    wds[j*41 + k] = Wd2[i];
  }
  if (t < D_OUT) bds[t] = bd2[t];
  __syncthreads();
  int wave = t >> 6, lane = t & 63;
  int node = blockIdx.x*4 + wave;
  if (node >= n) return;
  int grp = lane >> 4, fl = lane & 15;
  bool fa = fl < 10;                       // 10 float4 = 40 features
  const float4* h4 = (const float4*)hws2;
  float4 acc = make_float4(0.f, 0.f, 0.f, 0.f);
  if (grp == 0 && fa) acc = h4[(size_t)node*10 + fl];   // self loop
  int s0 = rs[node], cnt = deg[node];
  for (int cb = 0; cb < cnt; cb += 64){
    int m = cnt - cb; if (m > 64) m = 64;
    int idx = (lane < m) ? col[s0 + cb + lane] : 0;
    #pragma unroll 4
    for (int e0 = 0; e0 < m; e0 += 4){
      int sl = e0 + grp;
      int s = __shfl(idx, sl, 64);
      if (sl < m && fa){
        float4 v = h4[(size_t)s*10 + fl];
        acc.x += v.x; acc.y += v.y; acc.z += v.z; acc.w += v.w;
      }
    }
  }
  acc.x += __shfl_xor(acc.x, 16, 64); acc.y += __shfl_xor(acc.y, 16, 64);
  acc.z += __shfl_xor(acc.z, 16, 64); acc.w += __shfl_xor(acc.w, 16, 64);
  acc.x += __shfl_xor(acc.x, 32, 64); acc.y += __shfl_xor(acc.y, 32, 64);
  acc.z += __shfl_xor(acc.z, 32, 64); acc.w += __shfl_xor(acc.w, 32, 64);
  float dv = dinv[node];
  float4 res = make_float4(0.f, 0.f, 0.f, 0.f);
  if (fa){
    float4 b = ((const float4*)bc2)[fl];
    res.x = acc.x*dv + b.x;
    res.y = acc.y*dv + b.y;
    res.z = acc.z*dv + b.z;
    res.w = acc.w*dv + b.w;
  }
  if (mask[node] != 0){                    // wave-uniform branch
    float4 r;
    int j0 = fl*4;
    r.x = bds[(j0+0) < D_OUT ? j0+0 : 0];
    r.y = bds[(j0+1) < D_OUT ? j0+1 : 0];
    r.z = bds[(j0+2) < D_OUT ? j0+2 : 0];
    r.w = bds[(j0+3) < D_OUT ? j0+3 : 0];
    #pragma unroll
    for (int k4 = 0; k4 < 10; k4++){
      float ox = __shfl(res.x, k4, 64);    // sources are lanes 0..9 (valid res)
      float oy = __shfl(res.y, k4, 64);
      float oz = __shfl(res.z, k4, 64);
      float ow = __shfl(res.w, k4, 64);
      if (fa){
        int k = k4*4;
        const float* w0 = &wds[(j0+0)*41 + k];
        const float* w1 = &wds[(j0+1)*41 + k];
        const float* w2 = &wds[(j0+2)*41 + k];
        const float* w3 = &wds[(j0+3)*41 + k];
        r.x += ox*w0[0] + oy*w0[1] + oz*w0[2] + ow*w0[3];
        r.y += ox*w1[0] + oy*w1[1] + oz*w1[2] + ow*w1[3];
        r.z += ox*w2[0] + oy*w2[1] + oz*w2[2] + ow*w2[3];
        r.w += ox*w3[0] + oy*w3[1] + oz*w3[2] + ow*w3[3];
      }
    }
    if (fa) res = r;
  }
  if (grp == 0 && fa) ((float4*)out)[(size_t)node*10 + fl] = res;
}

// ---------------- launcher ----------------

extern "C" void kernel_launch(void* const* d_in, const int* in_sizes, int n_in,
                              void* d_out, int out_size, void* d_ws, size_t ws_size,
                              hipStream_t stream){
  const float* x    = (const float*)d_in[0];
  const int*   ei   = (const int*)d_in[1];
  const unsigned char* mask = (const unsigned char*)d_in[2];
  const float* Wc1  = (const float*)d_in[3];
  const float* bc1  = (const float*)d_in[4];
  const float* Wc2  = (const float*)d_in[5];
  const float* bc2  = (const float*)d_in[6];
  const float* Wd1  = (const float*)d_in[7];
  const float* bd1  = (const float*)d_in[8];
  const float* Wd2  = (const float*)d_in[9];
  const float* bd2  = (const float*)d_in[10];

  int N = in_sizes[0] / D_IN;
  int E = in_sizes[1] / 2;
  const int* src = ei;
  const int* dst = ei + E;
  float* out = (float*)d_out;

  char* w = (char*)d_ws; size_t off = 0;
  auto A = [&](size_t bytes)->void*{
    void* p = w + off;
    off += (bytes + 255) & ~(size_t)255;
    return p;
  };
  int*   deg    = (int*)  A((size_t)N*4);
  int*   rs     = (int*)  A((size_t)N*4);
  int*   cursor = (int*)  A((size_t)N*4);
  int*   bsums  = (int*)  A(256*4);
  float* dinv   = (float*)A((size_t)N*4);
  float* Mmat   = (float*)A((size_t)D_H*D_OUT*4);
  float* bvec   = (float*)A((size_t)D_OUT*4);
  int*   col    = (int*)  A((size_t)E*4);
  float* hws1   = (float*)A((size_t)N*D_H*4);
  float* h      = (float*)A((size_t)N*D_H*4);
  float* hws2   = hws1;   // hws1 dead after agg1 -> reuse

  int NB = (N + 1023) / 1024;

  hipMemsetAsync(deg, 0, (size_t)N*4, stream);
  hipLaunchKernelGGL(k_count, dim3((E+255)/256), dim3(256), 0, stream, dst, deg, E);
  hipLaunchKernelGGL(k_scan1, dim3(NB), dim3(1024), 0, stream, deg, rs, bsums, N);
  hipLaunchKernelGGL(k_scan2, dim3(1), dim3(128), 0, stream, bsums, NB);
  hipLaunchKernelGGL(k_scan3, dim3(NB), dim3(1024), 0, stream, deg, rs, bsums, cursor, dinv, N);
  hipLaunchKernelGGL(k_fill,  dim3((E+255)/256), dim3(256), 0, stream, src, dst, cursor, col, E);
  hipLaunchKernelGGL(k_pre,   dim3(1), dim3(256), 0, stream, Wd1, bd1, Wc2, Mmat, bvec);
  hipLaunchKernelGGL(k_gemm1, dim3((N+31)/32), dim3(256), 0, stream, x, Wc1, dinv, hws1, N);
  hipLaunchKernelGGL(k_agg1,  dim3((N+3)/4), dim3(256), 0, stream, hws1, rs, deg, col, dinv, bc1, h, N);
  hipLaunchKernelGGL(k_gemm2, dim3((N+127)/128), dim3(128), 0, stream, h, mask, Mmat, bvec, Wc2, dinv, hws2, N);
  hipLaunchKernelGGL(k_agg2,  dim3((N+3)/4), dim3(256), 0, stream, hws2, rs, deg, col, dinv, bc2, mask, Wd2, bd2, out, N);
}